// Round 1
// 73.414 us; speedup vs baseline: 1.0119x; 1.0119x over previous
//
#include <hip/hip_runtime.h>

// Problem constants
#define B_    8
#define C_    512
#define T_    512
#define O_    512
#define K_    65
#define PAD_  32

// Tiling: 8 waves/block, each wave owns J_=4 outputs x all 128 t (2 t/lane)
#define O_TILE 32
#define T_TILE 128
#define J_     4
#define NWAVE  8
#define NTHR   512
#define ROWS   (O_TILE + 2 * PAD_)   // 96 x-rows staged
#define NR_    (J_ + 2 * PAD_)       // 68 banded steps per output group
#define YPITCH 36

#define XTILE_ELEMS (ROWS * T_TILE)      // 12288 floats (48 KB)
#define WT_TILE     (NWAVE * NR_ * J_)   // 2176 floats (8.7 KB)

// Single fused kernel: no workspace, no second launch.
// LDS = 57856 B -> 2 blocks/CU -> 16 waves/CU (4/SIMD), 2x prior TLP.
__global__ __launch_bounds__(NTHR, 4)
void conv_fused(const float* __restrict__ x,
                const float* __restrict__ w,
                const float* __restrict__ bias,
                float* __restrict__ out) {
    __shared__ float smem[XTILE_ELEMS + WT_TILE];
    float* xs  = smem;
    float* wts = smem + XTILE_ELEMS;

    const int tid = threadIdx.x;
    const int bid = blockIdx.x;          // 512: b(8) x ob(16) x tb(4)
    const int b   = bid >> 6;
    const int rem = bid & 63;
    const int ob  = rem >> 2;
    const int tb  = rem & 3;
    const int t0  = tb * T_TILE;
    const int c_base = ob * O_TILE - PAD_;

    // ---- Stage x tile (96 rows x 128 cols, zero-padded rows outside [0,C)) ----
    {
        const float* xb = x + (size_t)b * (C_ * T_);
        const int l32 = tid & 31;        // col group (float4)
        const int rg  = tid >> 5;        // 0..15 row group
        #pragma unroll
        for (int rr = 0; rr < ROWS / 16; ++rr) {   // 6 iters
            const int row = rr * 16 + rg;
            const int c   = c_base + row;
            float4 v = make_float4(0.f, 0.f, 0.f, 0.f);
            if (c >= 0 && c < C_)
                v = *(const float4*)(xb + c * T_ + t0 + l32 * 4);
            *(float4*)(&xs[row * T_TILE + l32 * 4]) = v;
        }
    }

    // ---- Stage banded weight table: wts[g][r][j] = W[(ob*8+g)*4+j][r-j] ----
    {
        #pragma unroll
        for (int p = 0; p < (WT_TILE + NTHR - 1) / NTHR; ++p) {   // 5 iters
            const int e = p * NTHR + tid;
            if (e < WT_TILE) {
                const int g  = e / (NR_ * J_);
                const int r2 = e % (NR_ * J_);
                const int r  = r2 >> 2;
                const int j  = r2 & 3;
                const int o  = (ob * NWAVE + g) * J_ + j;
                const int k  = r - j;
                float v = 0.f;
                if (k >= 0 && k < K_) v = w[o * K_ + k];
                wts[e] = v;
            }
        }
    }
    __syncthreads();

    // ---- Compute: wave wu -> outputs [obase, obase+4), lane -> t pair ----
    const int lane = tid & 63;
    const int wu   = __builtin_amdgcn_readfirstlane(tid >> 6);  // uniform 0..7
    const int obase = ob * O_TILE + wu * J_;

    float2 acc[J_];
    #pragma unroll
    for (int j = 0; j < J_; ++j) {
        const float bj = bias[obase + j];   // uniform -> scalar load
        acc[j] = make_float2(bj, bj);
    }

    const int tl = lane * 2;
    const float* xrow = xs + (wu * J_) * T_TILE + tl;
    const float4* wrow = (const float4*)(wts) + wu * NR_;   // uniform addr -> LDS broadcast

    #pragma unroll 4
    for (int r = 0; r < NR_; ++r) {
        const float2 xv = *(const float2*)(xrow + r * T_TILE);
        const float4 wv = wrow[r];
        acc[0].x += wv.x * xv.x;  acc[0].y += wv.x * xv.y;
        acc[1].x += wv.y * xv.x;  acc[1].y += wv.y * xv.y;
        acc[2].x += wv.z * xv.x;  acc[2].y += wv.z * xv.y;
        acc[3].x += wv.w * xv.x;  acc[3].y += wv.w * xv.y;
    }

    __syncthreads();   // x tile dead; reuse smem as y tile [t][o], pitch YPITCH

    // ---- Transpose through LDS ----
    *(float4*)(&smem[tl * YPITCH + wu * J_])       = make_float4(acc[0].x, acc[1].x, acc[2].x, acc[3].x);
    *(float4*)(&smem[(tl + 1) * YPITCH + wu * J_]) = make_float4(acc[0].y, acc[1].y, acc[2].y, acc[3].y);
    __syncthreads();

    // ---- Coalesced global store ----
    {
        float* ob_out = out + (size_t)b * (T_ * O_) + (size_t)t0 * O_ + ob * O_TILE;
        const int ol   = (tid & 7) * 4;
        const int trow = tid >> 3;          // 0..63
        #pragma unroll
        for (int p = 0; p < 2; ++p) {
            const int t_local = p * 64 + trow;
            const float4 v = *(const float4*)(&smem[t_local * YPITCH + ol]);
            *(float4*)(ob_out + (size_t)t_local * O_ + ol) = v;
        }
    }
}

extern "C" void kernel_launch(void* const* d_in, const int* in_sizes, int n_in,
                              void* d_out, int out_size, void* d_ws, size_t ws_size,
                              hipStream_t stream) {
    const float* x    = (const float*)d_in[0];
    const float* w    = (const float*)d_in[1];
    const float* bias = (const float*)d_in[2];
    float* out = (float*)d_out;
    (void)d_ws; (void)ws_size;   // workspace intentionally unused: avoid 256 MiB re-poison fill

    const int nblocks = B_ * (O_ / O_TILE) * (T_ / T_TILE);   // 512
    conv_fused<<<nblocks, NTHR, 0, stream>>>(x, w, bias, out);
}